// Round 1
// baseline (1470.571 us; speedup 1.0000x reference)
//
#include <hip/hip_runtime.h>
#include <math.h>

// Problem constants
#define B_   8
#define N_   1024
#define FIN  512
#define FOUT 512
#define H_   8
#define HD_  64
#define BH_  64          // B_*H_

// Workspace layout (in floats)
#define OFF_WP   0                         // 3 * 512*512
#define OFF_Q    (3*512*512)               // 786432
#define OFF_K    (OFF_Q + 4194304)
#define OFF_V    (OFF_K + 4194304)
#define OFF_AMAX (OFF_V + 4194304)         // 3 uints: amax_q, amax_k, amax_attn

__device__ __forceinline__ float fq_val(float x, float scale) {
    float r = rintf(x / scale);                 // round half-to-even, matches jnp.round
    r = fminf(fmaxf(r, -127.f), 127.f);
    return r * scale;
}

__device__ __forceinline__ float dot4f(float4 a, float4 b, float acc) {
    acc = fmaf(a.x, b.x, acc);
    acc = fmaf(a.y, b.y, acc);
    acc = fmaf(a.z, b.z, acc);
    acc = fmaf(a.w, b.w, acc);
    return acc;
}

__device__ __forceinline__ void outer4(float (&acc)[4][4], float4 a, float4 b) {
    float av[4] = {a.x, a.y, a.z, a.w};
    float bv[4] = {b.x, b.y, b.z, b.w};
#pragma unroll
    for (int i = 0; i < 4; ++i)
#pragma unroll
        for (int j = 0; j < 4; ++j)
            acc[i][j] = fmaf(av[i], bv[j], acc[i][j]);
}

// ---------------------------------------------------------------------------
// K1: Wp = mag[o] / ||W[o,:] + Bm[o,:]@A||  *  (W[o,:] + Bm[o,:]@A)
// one block (256 thr) per output row o
// ---------------------------------------------------------------------------
__global__ __launch_bounds__(256) void build_wp_k(
    const float* __restrict__ W, const float* __restrict__ A,
    const float* __restrict__ Bm, const float* __restrict__ mag,
    float* __restrict__ Wp)
{
    __shared__ float brow[16];
    __shared__ __align__(16) float wd[512];
    __shared__ float red[5];
    int o = blockIdx.x;
    int tid = threadIdx.x;
    if (tid < 16) brow[tid] = Bm[o * 16 + tid];
    __syncthreads();
    float ss = 0.f;
    for (int i = tid; i < 512; i += 256) {
        float acc = W[o * 512 + i];
#pragma unroll
        for (int r = 0; r < 16; ++r) acc = fmaf(brow[r], A[r * 512 + i], acc);
        wd[i] = acc;
        ss = fmaf(acc, acc, ss);
    }
#pragma unroll
    for (int off = 32; off > 0; off >>= 1) ss += __shfl_down(ss, off);
    int lane = tid & 63, wv = tid >> 6;
    if (lane == 0) red[wv] = ss;
    __syncthreads();
    if (tid == 0) red[4] = mag[o] / sqrtf(red[0] + red[1] + red[2] + red[3]);
    __syncthreads();
    float scl = red[4];
    for (int i = tid; i < 512; i += 256) Wp[o * 512 + i] = wd[i] * scl;
}

// ---------------------------------------------------------------------------
// K2: y = x(8192x512) @ Wp^T(512x512), dst written in (b,h,n,d) layout.
// 64x64 tile, BK=16, 4x4 per thread. Optional per-tensor absmax via atomicMax.
// ---------------------------------------------------------------------------
__global__ __launch_bounds__(256) void proj_gemm_k(
    const float* __restrict__ x, const float* __restrict__ Wp,
    float* __restrict__ dst, unsigned int* __restrict__ amaxp, int do_amax)
{
    __shared__ __align__(16) float xs[16][68];
    __shared__ __align__(16) float wsb[16][68];
    __shared__ float redmax[4];
    int tid = threadIdx.x;
    int tx = tid & 15, ty = tid >> 4;
    int t0 = blockIdx.x * 64, o0 = blockIdx.y * 64;
    float acc[4][4];
#pragma unroll
    for (int i = 0; i < 4; ++i)
#pragma unroll
        for (int j = 0; j < 4; ++j) acc[i][j] = 0.f;

    int r = tid >> 2, c4 = tid & 3;
    for (int k0 = 0; k0 < 512; k0 += 16) {
        float4 xv = *(const float4*)(x + (size_t)(t0 + r) * 512 + k0 + c4 * 4);
        float4 wv = *(const float4*)(Wp + (size_t)(o0 + r) * 512 + k0 + c4 * 4);
        xs[c4 * 4 + 0][r] = xv.x; xs[c4 * 4 + 1][r] = xv.y;
        xs[c4 * 4 + 2][r] = xv.z; xs[c4 * 4 + 3][r] = xv.w;
        wsb[c4 * 4 + 0][r] = wv.x; wsb[c4 * 4 + 1][r] = wv.y;
        wsb[c4 * 4 + 2][r] = wv.z; wsb[c4 * 4 + 3][r] = wv.w;
        __syncthreads();
#pragma unroll
        for (int kk = 0; kk < 16; ++kk) {
            float4 a = *(const float4*)&xs[kk][ty * 4];
            float4 b = *(const float4*)&wsb[kk][tx * 4];
            outer4(acc, a, b);
        }
        __syncthreads();
    }

    int h = o0 >> 6;
    float mx = 0.f;
#pragma unroll
    for (int i = 0; i < 4; ++i) {
        int t = t0 + ty * 4 + i;
        int b = t >> 10, n = t & 1023;
        float4 v4 = make_float4(acc[i][0], acc[i][1], acc[i][2], acc[i][3]);
        *(float4*)(dst + ((size_t)(b * 8 + h) * 1024 + n) * 64 + tx * 4) = v4;
        mx = fmaxf(mx, fmaxf(fmaxf(fabsf(v4.x), fabsf(v4.y)),
                             fmaxf(fabsf(v4.z), fabsf(v4.w))));
    }
    if (do_amax) {
#pragma unroll
        for (int off = 32; off > 0; off >>= 1) mx = fmaxf(mx, __shfl_down(mx, off));
        if ((tid & 63) == 0) redmax[tid >> 6] = mx;
        __syncthreads();
        if (tid == 0) {
            float m2 = fmaxf(fmaxf(redmax[0], redmax[1]), fmaxf(redmax[2], redmax[3]));
            atomicMax(amaxp, __float_as_uint(m2));
        }
    }
}

// ---------------------------------------------------------------------------
// K2b: in-place fake_quant of a tensor given its absmax
// ---------------------------------------------------------------------------
__global__ __launch_bounds__(256) void quant_inplace_k(
    float* __restrict__ p, const unsigned int* __restrict__ amaxp, int n4)
{
    float scale = fmaxf(__uint_as_float(*amaxp) / 127.f, 1e-8f);
    int i = blockIdx.x * 256 + threadIdx.x;
    if (i < n4) {
        float4* p4 = (float4*)p;
        float4 v = p4[i];
        v.x = fq_val(v.x, scale); v.y = fq_val(v.y, scale);
        v.z = fq_val(v.z, scale); v.w = fq_val(v.w, scale);
        p4[i] = v;
    }
}

// ---------------------------------------------------------------------------
// K3: scores (quantized q . quantized k) + adj mask + softmax per row.
// Block = 8 rows of one (b,h). Wave w handles rows w and w+4.
// Writes raw softmax to d_out attn region; atomicMax of per-row max (=1/sum).
// ---------------------------------------------------------------------------
__global__ __launch_bounds__(256) void attn_rows_k(
    const float* __restrict__ qws, const float* __restrict__ kws,
    const int* __restrict__ adj, float* __restrict__ attn,
    unsigned int* __restrict__ amax_attn)
{
    __shared__ __align__(16) float qs[8][64];
    __shared__ __align__(16) float kt[64][64];   // column-group swizzled
    __shared__ __align__(16) float sc[8][1024];
    int tid = threadIdx.x;
    int xb = blockIdx.x;
    int h = xb & 7, nt = (xb >> 3) & 127, b = xb >> 10;
    int bh = b * 8 + h;
    int n0 = nt * 8;

    for (int i = tid; i < 512; i += 256)
        qs[i >> 6][i & 63] = qws[((size_t)bh * 1024 + n0) * 64 + i];

    int wv = tid >> 6, lane = tid & 63;
    int r1 = wv + 4;

    for (int mt = 0; mt < 16; ++mt) {
        const float* ksrc = kws + ((size_t)bh * 1024 + mt * 64) * 64;
#pragma unroll
        for (int l = 0; l < 4; ++l) {
            int idx = l * 256 + tid;
            int rm = idx >> 4, c4 = idx & 15;
            float4 kv = *(const float4*)(ksrc + rm * 64 + c4 * 4);
            *(float4*)&kt[rm][((c4 + rm) & 15) * 4] = kv;
        }
        __syncthreads();
        int m = mt * 64 + lane;
        float acc0 = 0.f, acc1 = 0.f;
#pragma unroll
        for (int d4 = 0; d4 < 16; ++d4) {
            float4 kv = *(const float4*)&kt[lane][((d4 + lane) & 15) * 4];
            float4 q0 = *(const float4*)&qs[wv][d4 * 4];
            float4 q1 = *(const float4*)&qs[r1][d4 * 4];
            acc0 = dot4f(kv, q0, acc0);
            acc1 = dot4f(kv, q1, acc1);
        }
        int a0 = adj[((size_t)b * 1024 + n0 + wv) * 1024 + m];
        int a1 = adj[((size_t)b * 1024 + n0 + r1) * 1024 + m];
        sc[wv][m] = a0 ? acc0 : -1e9f;
        sc[r1][m] = a1 ? acc1 : -1e9f;
        __syncthreads();
    }

#pragma unroll
    for (int rr = 0; rr < 2; ++rr) {
        int row = wv + rr * 4;
        float mx = -3.4e38f;
#pragma unroll
        for (int j = 0; j < 16; ++j) mx = fmaxf(mx, sc[row][j * 64 + lane]);
#pragma unroll
        for (int off = 32; off > 0; off >>= 1) mx = fmaxf(mx, __shfl_down(mx, off));
        mx = __shfl(mx, 0);
        float e[16];
        float sum = 0.f;
#pragma unroll
        for (int j = 0; j < 16; ++j) {
            e[j] = expf(sc[row][j * 64 + lane] - mx);
            sum += e[j];
        }
#pragma unroll
        for (int off = 32; off > 0; off >>= 1) sum += __shfl_down(sum, off);
        sum = __shfl(sum, 0);
        float* dst = attn + ((size_t)bh * 1024 + n0 + row) * 1024;
#pragma unroll
        for (int j = 0; j < 16; ++j) dst[j * 64 + lane] = e[j] / sum;
        if (lane == 0) atomicMax(amax_attn, __float_as_uint(1.f / sum));
    }
}

// ---------------------------------------------------------------------------
// K4: fake_quant(attn) written back to d_out (output 1) fused with
// out = attn_q @ v (output 0, (b,n,h*64+d) layout). 64x64 tile per block.
// ---------------------------------------------------------------------------
__global__ __launch_bounds__(256) void attn_v_k(
    float* __restrict__ attn, const float* __restrict__ vws,
    float* __restrict__ out, const unsigned int* __restrict__ amax_attn)
{
    __shared__ __align__(16) float atT[64][68];  // [m_local][n_local]
    __shared__ __align__(16) float vt[64][68];   // [m_local][d]
    int tid = threadIdx.x;
    int nt = blockIdx.x, bh = blockIdx.y;
    int b = bh >> 3, h = bh & 7;
    int n0 = nt * 64;
    float sa = fmaxf(__uint_as_float(*amax_attn) / 127.f, 1e-8f);
    int tx = tid & 15, ty = tid >> 4;
    float acc[4][4];
#pragma unroll
    for (int i = 0; i < 4; ++i)
#pragma unroll
        for (int j = 0; j < 4; ++j) acc[i][j] = 0.f;

    float* abase = attn + ((size_t)bh * 1024 + n0) * 1024;
    const float* vbase = vws + (size_t)bh * 1024 * 64;

    for (int mt = 0; mt < 16; ++mt) {
#pragma unroll
        for (int l = 0; l < 4; ++l) {
            int idx = l * 256 + tid;
            int rn = idx >> 4, c4 = idx & 15;
            float* ap = abase + (size_t)rn * 1024 + mt * 64 + c4 * 4;
            float4 av = *(float4*)ap;
            av.x = fq_val(av.x, sa); av.y = fq_val(av.y, sa);
            av.z = fq_val(av.z, sa); av.w = fq_val(av.w, sa);
            *(float4*)ap = av;                      // quantized attn = output 1
            atT[c4 * 4 + 0][rn] = av.x; atT[c4 * 4 + 1][rn] = av.y;
            atT[c4 * 4 + 2][rn] = av.z; atT[c4 * 4 + 3][rn] = av.w;
            float4 vv = *(const float4*)(vbase + (size_t)(mt * 64 + rn) * 64 + c4 * 4);
            *(float4*)&vt[rn][c4 * 4] = vv;
        }
        __syncthreads();
#pragma unroll 16
        for (int kk = 0; kk < 64; ++kk) {
            float4 a = *(const float4*)&atT[kk][ty * 4];
            float4 bv = *(const float4*)&vt[kk][tx * 4];
            outer4(acc, a, bv);
        }
        __syncthreads();
    }
#pragma unroll
    for (int i = 0; i < 4; ++i) {
        int n = n0 + ty * 4 + i;
        *(float4*)(out + ((size_t)b * 1024 + n) * 512 + h * 64 + tx * 4) =
            make_float4(acc[i][0], acc[i][1], acc[i][2], acc[i][3]);
    }
}

// ---------------------------------------------------------------------------
extern "C" void kernel_launch(void* const* d_in, const int* in_sizes, int n_in,
                              void* d_out, int out_size, void* d_ws, size_t ws_size,
                              hipStream_t stream)
{
    (void)in_sizes; (void)n_in; (void)out_size; (void)ws_size;
    const float* x    = (const float*)d_in[0];
    const int*   adj  = (const int*)d_in[1];
    const float* W_q = (const float*)d_in[2];
    const float* A_q = (const float*)d_in[3];
    const float* B_q = (const float*)d_in[4];
    const float* m_q = (const float*)d_in[5];
    const float* W_k = (const float*)d_in[6];
    const float* A_k = (const float*)d_in[7];
    const float* B_k = (const float*)d_in[8];
    const float* m_k = (const float*)d_in[9];
    const float* W_v = (const float*)d_in[10];
    const float* A_v = (const float*)d_in[11];
    const float* B_v = (const float*)d_in[12];
    const float* m_v = (const float*)d_in[13];

    float* ws = (float*)d_ws;
    float* wp_q = ws + OFF_WP;
    float* wp_k = ws + OFF_WP + 262144;
    float* wp_v = ws + OFF_WP + 524288;
    float* qb = ws + OFF_Q;
    float* kb = ws + OFF_K;
    float* vb = ws + OFF_V;
    unsigned int* amax = (unsigned int*)(ws + OFF_AMAX);

    float* out_base  = (float*)d_out;                 // (b, n, h*64+d)
    float* attn_base = out_base + 4194304;            // (b, h, n, m)

    hipMemsetAsync(amax, 0, 3 * sizeof(unsigned int), stream);

    build_wp_k<<<512, 256, 0, stream>>>(W_q, A_q, B_q, m_q, wp_q);
    build_wp_k<<<512, 256, 0, stream>>>(W_k, A_k, B_k, m_k, wp_k);
    build_wp_k<<<512, 256, 0, stream>>>(W_v, A_v, B_v, m_v, wp_v);

    proj_gemm_k<<<dim3(128, 8), 256, 0, stream>>>(x, wp_q, qb, amax + 0, 1);
    proj_gemm_k<<<dim3(128, 8), 256, 0, stream>>>(x, wp_k, kb, amax + 1, 1);
    proj_gemm_k<<<dim3(128, 8), 256, 0, stream>>>(x, wp_v, vb, amax + 2, 0);

    quant_inplace_k<<<4096, 256, 0, stream>>>(qb, amax + 0, 1048576);
    quant_inplace_k<<<4096, 256, 0, stream>>>(kb, amax + 1, 1048576);

    attn_rows_k<<<8192, 256, 0, stream>>>(qb, kb, adj, attn_base, amax + 2);

    attn_v_k<<<dim3(16, 64), 256, 0, stream>>>(attn_base, vb, out_base, amax + 2);
}

// Round 2
// 835.249 us; speedup vs baseline: 1.7606x; 1.7606x over previous
//
#include <hip/hip_runtime.h>
#include <math.h>

// Problem constants: B=8, N=1024, FIN=FOUT=512, H=8, HD=64, BH=64

typedef __attribute__((ext_vector_type(8))) short short8;    // 8 bf16 (4 VGPRs)
typedef __attribute__((ext_vector_type(4))) float floatx4;   // MFMA C/D

// Workspace layout (float words)
#define OFF_WP    0                // 262144  (single reused W' buffer)
#define OFF_RAW   262144           // 4194304 (reused raw q/k/v projection)
#define OFF_QLV   4456448          // 2097152 floats = 4.2M bf16 levels
#define OFF_KLV   6553600
#define OFF_VTH   8650752          // v^T hi bf16 [bh][d][m]
#define OFF_VTL   10747904         // v^T lo bf16
#define OFF_RS    12845056         // 65536 float2 (row m, l)
#define OFF_AMAX  12976128         // 3 uints

__device__ __forceinline__ unsigned short bf16_rne(float f) {
    unsigned int u = __float_as_uint(f);
    unsigned int r = u + 0x7fffu + ((u >> 16) & 1u);
    return (unsigned short)(r >> 16);
}
__device__ __forceinline__ float bf16_to_f(unsigned short h) {
    return __uint_as_float(((unsigned int)h) << 16);
}
// exact for values already representable in bf16 (integers |x|<=127)
__device__ __forceinline__ unsigned short bf16_exact(float f) {
    return (unsigned short)(__float_as_uint(f) >> 16);
}

__device__ __forceinline__ void outer4(float (&acc)[4][4], float4 a, float4 b) {
    float av[4] = {a.x, a.y, a.z, a.w};
    float bv[4] = {b.x, b.y, b.z, b.w};
#pragma unroll
    for (int i = 0; i < 4; ++i)
#pragma unroll
        for (int j = 0; j < 4; ++j)
            acc[i][j] = fmaf(av[i], bv[j], acc[i][j]);
}

// ---------------------------------------------------------------------------
// K1: Wp row o = mag[o]/||W[o,:]+Bm[o,:]@A|| * (W[o,:]+Bm[o,:]@A)
// ---------------------------------------------------------------------------
__global__ __launch_bounds__(256) void build_wp_k(
    const float* __restrict__ W, const float* __restrict__ A,
    const float* __restrict__ Bm, const float* __restrict__ mag,
    float* __restrict__ Wp)
{
    __shared__ float brow[16];
    __shared__ __align__(16) float wd[512];
    __shared__ float red[5];
    int o = blockIdx.x;
    int tid = threadIdx.x;
    if (tid < 16) brow[tid] = Bm[o * 16 + tid];
    __syncthreads();
    float ss = 0.f;
    for (int i = tid; i < 512; i += 256) {
        float acc = W[o * 512 + i];
#pragma unroll
        for (int r = 0; r < 16; ++r) acc = fmaf(brow[r], A[r * 512 + i], acc);
        wd[i] = acc;
        ss = fmaf(acc, acc, ss);
    }
#pragma unroll
    for (int off = 32; off > 0; off >>= 1) ss += __shfl_down(ss, off);
    int lane = tid & 63, wv = tid >> 6;
    if (lane == 0) red[wv] = ss;
    __syncthreads();
    if (tid == 0) red[4] = mag[o] / sqrtf(red[0] + red[1] + red[2] + red[3]);
    __syncthreads();
    float scl = red[4];
    for (int i = tid; i < 512; i += 256) Wp[o * 512 + i] = wd[i] * scl;
}

// ---------------------------------------------------------------------------
// K2: y = x(8192x512) @ Wp^T, dst in (b,h,n,d) layout; optional absmax.
// ---------------------------------------------------------------------------
__global__ __launch_bounds__(256) void proj_gemm_k(
    const float* __restrict__ x, const float* __restrict__ Wp,
    float* __restrict__ dst, unsigned int* __restrict__ amaxp, int do_amax)
{
    __shared__ __align__(16) float xs[16][68];
    __shared__ __align__(16) float wsb[16][68];
    __shared__ float redmax[4];
    int tid = threadIdx.x;
    int tx = tid & 15, ty = tid >> 4;
    int t0 = blockIdx.x * 64, o0 = blockIdx.y * 64;
    float acc[4][4];
#pragma unroll
    for (int i = 0; i < 4; ++i)
#pragma unroll
        for (int j = 0; j < 4; ++j) acc[i][j] = 0.f;

    int r = tid >> 2, c4 = tid & 3;
    for (int k0 = 0; k0 < 512; k0 += 16) {
        float4 xv = *(const float4*)(x + (size_t)(t0 + r) * 512 + k0 + c4 * 4);
        float4 wv = *(const float4*)(Wp + (size_t)(o0 + r) * 512 + k0 + c4 * 4);
        xs[c4 * 4 + 0][r] = xv.x; xs[c4 * 4 + 1][r] = xv.y;
        xs[c4 * 4 + 2][r] = xv.z; xs[c4 * 4 + 3][r] = xv.w;
        wsb[c4 * 4 + 0][r] = wv.x; wsb[c4 * 4 + 1][r] = wv.y;
        wsb[c4 * 4 + 2][r] = wv.z; wsb[c4 * 4 + 3][r] = wv.w;
        __syncthreads();
#pragma unroll
        for (int kk = 0; kk < 16; ++kk) {
            float4 a = *(const float4*)&xs[kk][ty * 4];
            float4 b = *(const float4*)&wsb[kk][tx * 4];
            outer4(acc, a, b);
        }
        __syncthreads();
    }

    int h = o0 >> 6;
    float mx = 0.f;
#pragma unroll
    for (int i = 0; i < 4; ++i) {
        int t = t0 + ty * 4 + i;
        int b = t >> 10, n = t & 1023;
        float4 v4 = make_float4(acc[i][0], acc[i][1], acc[i][2], acc[i][3]);
        *(float4*)(dst + ((size_t)(b * 8 + h) * 1024 + n) * 64 + tx * 4) = v4;
        mx = fmaxf(mx, fmaxf(fmaxf(fabsf(v4.x), fabsf(v4.y)),
                             fmaxf(fabsf(v4.z), fabsf(v4.w))));
    }
    if (do_amax) {
#pragma unroll
        for (int off = 32; off > 0; off >>= 1) mx = fmaxf(mx, __shfl_down(mx, off));
        if ((tid & 63) == 0) redmax[tid >> 6] = mx;
        __syncthreads();
        if (tid == 0) {
            float m2 = fmaxf(fmaxf(redmax[0], redmax[1]), fmaxf(redmax[2], redmax[3]));
            atomicMax(amaxp, __float_as_uint(m2));
        }
    }
}

// ---------------------------------------------------------------------------
// K2b: raw fp32 -> int8 levels stored as exact bf16 (for MFMA operands)
// ---------------------------------------------------------------------------
__global__ __launch_bounds__(256) void quant_levels_k(
    const float* __restrict__ raw, const unsigned int* __restrict__ amaxp,
    unsigned short* __restrict__ lv, int n4)
{
    float scale = fmaxf(__uint_as_float(*amaxp) / 127.f, 1e-8f);
    int i = blockIdx.x * 256 + threadIdx.x;
    if (i >= n4) return;
    float4 v = ((const float4*)raw)[i];
    float l0 = fminf(fmaxf(rintf(v.x / scale), -127.f), 127.f);
    float l1 = fminf(fmaxf(rintf(v.y / scale), -127.f), 127.f);
    float l2 = fminf(fmaxf(rintf(v.z / scale), -127.f), 127.f);
    float l3 = fminf(fmaxf(rintf(v.w / scale), -127.f), 127.f);
    ushort4 o;
    o.x = bf16_exact(l0); o.y = bf16_exact(l1);
    o.z = bf16_exact(l2); o.w = bf16_exact(l3);
    ((ushort4*)lv)[i] = o;
}

// ---------------------------------------------------------------------------
// K2c: v (bh,n,64) fp32 -> transposed bf16 hi/lo (bh,d=64,m=1024)
// ---------------------------------------------------------------------------
__global__ __launch_bounds__(256) void vsplit_k(
    const float* __restrict__ vb, unsigned short* __restrict__ vth,
    unsigned short* __restrict__ vtl)
{
    __shared__ float ls[64][69];
    int tid = threadIdx.x;
    int mt = blockIdx.x, bh = blockIdx.y;
#pragma unroll
    for (int l = 0; l < 4; ++l) {
        int idx = l * 256 + tid;
        int r = idx >> 4, c4 = idx & 15;
        float4 v = *(const float4*)(vb + (size_t)(bh * 1024 + mt * 64 + r) * 64 + c4 * 4);
        ls[r][c4 * 4 + 0] = v.x; ls[r][c4 * 4 + 1] = v.y;
        ls[r][c4 * 4 + 2] = v.z; ls[r][c4 * 4 + 3] = v.w;
    }
    __syncthreads();
#pragma unroll
    for (int l = 0; l < 4; ++l) {
        int idx = l * 256 + tid;
        int d = idx >> 4, mg = idx & 15;
        ushort4 hi, lo;
        float v0 = ls[mg * 4 + 0][d], v1 = ls[mg * 4 + 1][d];
        float v2 = ls[mg * 4 + 2][d], v3 = ls[mg * 4 + 3][d];
        hi.x = bf16_rne(v0); lo.x = bf16_rne(v0 - bf16_to_f(hi.x));
        hi.y = bf16_rne(v1); lo.y = bf16_rne(v1 - bf16_to_f(hi.y));
        hi.z = bf16_rne(v2); lo.z = bf16_rne(v2 - bf16_to_f(hi.z));
        hi.w = bf16_rne(v3); lo.w = bf16_rne(v3 - bf16_to_f(hi.w));
        size_t ob = (size_t)(bh * 64 + d) * 1024 + mt * 64 + mg * 4;
        *(ushort4*)(vth + ob) = hi;
        *(ushort4*)(vtl + ob) = lo;
    }
}

// ---------------------------------------------------------------------------
// K3a: MFMA scores + adj mask + per-row online softmax stats (m, l).
// Block = (bh, 64 q rows); 4 waves x 16 rows. Also attn amax = max 1/l.
// ---------------------------------------------------------------------------
__global__ __launch_bounds__(256) void attn_stats_k(
    const unsigned short* __restrict__ qlv, const unsigned short* __restrict__ klv,
    const int* __restrict__ adj, const unsigned int* __restrict__ amax,
    float2* __restrict__ rowstats, unsigned int* __restrict__ amax_attn)
{
    __shared__ unsigned short qs[64][72];
    __shared__ unsigned short kt[64][72];
    int tid = threadIdx.x;
    int qt = blockIdx.x, bh = blockIdx.y;
    int b = bh >> 3;
    int n0 = qt * 64;
    float sq = fmaxf(__uint_as_float(amax[0]) / 127.f, 1e-8f);
    float sk = fmaxf(__uint_as_float(amax[1]) / 127.f, 1e-8f);
    float ss = sq * sk;

#pragma unroll
    for (int l = 0; l < 2; ++l) {
        int idx = l * 256 + tid;
        int r = idx >> 3, g = idx & 7;
        *(uint4*)&qs[r][g * 8] =
            *(const uint4*)(qlv + (size_t)(bh * 1024 + n0 + r) * 64 + g * 8);
    }
    __syncthreads();

    int lane = tid & 63, w = tid >> 6;
    int m_ = lane & 15, quad = lane >> 4;
    short8 Aq0 = *(const short8*)&qs[w * 16 + m_][quad * 8];
    short8 Aq1 = *(const short8*)&qs[w * 16 + m_][32 + quad * 8];

    float mrun[4], lrun[4];
#pragma unroll
    for (int r = 0; r < 4; ++r) { mrun[r] = -1e9f; lrun[r] = 0.f; }

    for (int c = 0; c < 16; ++c) {
        int m0 = c * 64;
        __syncthreads();
#pragma unroll
        for (int l = 0; l < 2; ++l) {
            int idx = l * 256 + tid;
            int r = idx >> 3, g = idx & 7;
            *(uint4*)&kt[r][g * 8] =
                *(const uint4*)(klv + (size_t)(bh * 1024 + m0 + r) * 64 + g * 8);
        }
        __syncthreads();
#pragma unroll
        for (int s = 0; s < 4; ++s) {
            short8 B0 = *(const short8*)&kt[s * 16 + m_][quad * 8];
            short8 B1 = *(const short8*)&kt[s * 16 + m_][32 + quad * 8];
            floatx4 Cv = {0.f, 0.f, 0.f, 0.f};
            Cv = __builtin_amdgcn_mfma_f32_16x16x32_bf16(Aq0, B0, Cv, 0, 0, 0);
            Cv = __builtin_amdgcn_mfma_f32_16x16x32_bf16(Aq1, B1, Cv, 0, 0, 0);
            int col = m0 + s * 16 + m_;
#pragma unroll
            for (int r = 0; r < 4; ++r) {
                int qrow = n0 + w * 16 + quad * 4 + r;
                int a = adj[((size_t)b << 20) + ((size_t)qrow << 10) + col];
                float sval = a ? Cv[r] * ss : -1e9f;
                float mn = fmaxf(mrun[r], sval);
                lrun[r] = lrun[r] * __expf(mrun[r] - mn) + __expf(sval - mn);
                mrun[r] = mn;
            }
        }
    }
#pragma unroll
    for (int r = 0; r < 4; ++r) {
        float m = mrun[r], l = lrun[r];
#pragma unroll
        for (int off = 1; off < 16; off <<= 1) {
            float mo = __shfl_xor(m, off);
            float lo = __shfl_xor(l, off);
            float mn = fmaxf(m, mo);
            l = l * __expf(m - mn) + lo * __expf(mo - mn);
            m = mn;
        }
        if (m_ == 0) {
            size_t row = (size_t)bh * 1024 + n0 + w * 16 + quad * 4 + r;
            rowstats[row] = make_float2(m, l);
            atomicMax(amax_attn, __float_as_uint(1.0f / l));
        }
    }
}

// ---------------------------------------------------------------------------
// K3b: recompute scores (bit-identical), p=exp(s-m)/l, quantize with global
// scale -> write attn output once; fused P@V via MFMA (v = bf16 hi+lo).
// ---------------------------------------------------------------------------
__global__ __launch_bounds__(256) void attn_out_k(
    const unsigned short* __restrict__ qlv, const unsigned short* __restrict__ klv,
    const unsigned short* __restrict__ vth, const unsigned short* __restrict__ vtl,
    const int* __restrict__ adj, const unsigned int* __restrict__ amax,
    const float2* __restrict__ rowstats,
    float* __restrict__ attn, float* __restrict__ out)
{
    __shared__ unsigned short qs[64][72];
    __shared__ unsigned short kt[64][72];
    __shared__ unsigned short pl[64][72];
    __shared__ unsigned short vh[64][72];
    __shared__ unsigned short vl[64][72];
    int tid = threadIdx.x;
    int qt = blockIdx.x, bh = blockIdx.y;
    int b = bh >> 3, h = bh & 7;
    int n0 = qt * 64;
    float sq = fmaxf(__uint_as_float(amax[0]) / 127.f, 1e-8f);
    float sk = fmaxf(__uint_as_float(amax[1]) / 127.f, 1e-8f);
    float ss = sq * sk;
    float sa = fmaxf(__uint_as_float(amax[2]) / 127.f, 1e-8f);
    float inv_sa = 1.0f / sa;

#pragma unroll
    for (int l = 0; l < 2; ++l) {
        int idx = l * 256 + tid;
        int r = idx >> 3, g = idx & 7;
        *(uint4*)&qs[r][g * 8] =
            *(const uint4*)(qlv + (size_t)(bh * 1024 + n0 + r) * 64 + g * 8);
    }
    __syncthreads();

    int lane = tid & 63, w = tid >> 6;
    int m_ = lane & 15, quad = lane >> 4;
    short8 Aq0 = *(const short8*)&qs[w * 16 + m_][quad * 8];
    short8 Aq1 = *(const short8*)&qs[w * 16 + m_][32 + quad * 8];

    float mrow[4], rlr[4];
#pragma unroll
    for (int r = 0; r < 4; ++r) {
        float2 st = rowstats[(size_t)bh * 1024 + n0 + w * 16 + quad * 4 + r];
        mrow[r] = st.x;
        rlr[r] = 1.0f / st.y;
    }
    floatx4 acc[4];
#pragma unroll
    for (int r = 0; r < 4; ++r) acc[r] = (floatx4){0.f, 0.f, 0.f, 0.f};

    for (int c = 0; c < 16; ++c) {
        int m0 = c * 64;
        __syncthreads();
#pragma unroll
        for (int l = 0; l < 2; ++l) {
            int idx = l * 256 + tid;
            int r = idx >> 3, g = idx & 7;
            *(uint4*)&kt[r][g * 8] =
                *(const uint4*)(klv + (size_t)(bh * 1024 + m0 + r) * 64 + g * 8);
            *(uint4*)&vh[r][g * 8] =
                *(const uint4*)(vth + (size_t)(bh * 64 + r) * 1024 + m0 + g * 8);
            *(uint4*)&vl[r][g * 8] =
                *(const uint4*)(vtl + (size_t)(bh * 64 + r) * 1024 + m0 + g * 8);
        }
        __syncthreads();
#pragma unroll
        for (int s = 0; s < 4; ++s) {
            short8 B0 = *(const short8*)&kt[s * 16 + m_][quad * 8];
            short8 B1 = *(const short8*)&kt[s * 16 + m_][32 + quad * 8];
            floatx4 Cv = {0.f, 0.f, 0.f, 0.f};
            Cv = __builtin_amdgcn_mfma_f32_16x16x32_bf16(Aq0, B0, Cv, 0, 0, 0);
            Cv = __builtin_amdgcn_mfma_f32_16x16x32_bf16(Aq1, B1, Cv, 0, 0, 0);
            int col = m0 + s * 16 + m_;
#pragma unroll
            for (int r = 0; r < 4; ++r) {
                int qrow = n0 + w * 16 + quad * 4 + r;
                int a = adj[((size_t)b << 20) + ((size_t)qrow << 10) + col];
                float sval = a ? Cv[r] * ss : -1e9f;
                float p = __expf(sval - mrow[r]) * rlr[r];
                float lv = fminf(rintf(p * inv_sa), 127.f);
                attn[((size_t)bh << 20) + ((size_t)qrow << 10) + col] = lv * sa;
                pl[w * 16 + quad * 4 + r][s * 16 + m_] = bf16_exact(lv);
            }
        }
        __syncthreads();
        short8 Ap0 = *(const short8*)&pl[w * 16 + m_][quad * 8];
        short8 Ap1 = *(const short8*)&pl[w * 16 + m_][32 + quad * 8];
#pragma unroll
        for (int dt = 0; dt < 4; ++dt) {
            short8 Bh0 = *(const short8*)&vh[dt * 16 + m_][quad * 8];
            short8 Bh1 = *(const short8*)&vh[dt * 16 + m_][32 + quad * 8];
            short8 Bl0 = *(const short8*)&vl[dt * 16 + m_][quad * 8];
            short8 Bl1 = *(const short8*)&vl[dt * 16 + m_][32 + quad * 8];
            acc[dt] = __builtin_amdgcn_mfma_f32_16x16x32_bf16(Ap0, Bh0, acc[dt], 0, 0, 0);
            acc[dt] = __builtin_amdgcn_mfma_f32_16x16x32_bf16(Ap1, Bh1, acc[dt], 0, 0, 0);
            acc[dt] = __builtin_amdgcn_mfma_f32_16x16x32_bf16(Ap0, Bl0, acc[dt], 0, 0, 0);
            acc[dt] = __builtin_amdgcn_mfma_f32_16x16x32_bf16(Ap1, Bl1, acc[dt], 0, 0, 0);
        }
    }
#pragma unroll
    for (int dt = 0; dt < 4; ++dt)
#pragma unroll
        for (int r = 0; r < 4; ++r) {
            int n = n0 + w * 16 + quad * 4 + r;
            int d = dt * 16 + m_;
            out[(size_t)(b * 1024 + n) * 512 + h * 64 + d] = acc[dt][r] * sa;
        }
}

// ---------------------------------------------------------------------------
extern "C" void kernel_launch(void* const* d_in, const int* in_sizes, int n_in,
                              void* d_out, int out_size, void* d_ws, size_t ws_size,
                              hipStream_t stream)
{
    (void)in_sizes; (void)n_in; (void)out_size; (void)ws_size;
    const float* x   = (const float*)d_in[0];
    const int*   adj = (const int*)d_in[1];
    const float* W_q = (const float*)d_in[2];
    const float* A_q = (const float*)d_in[3];
    const float* B_q = (const float*)d_in[4];
    const float* m_q = (const float*)d_in[5];
    const float* W_k = (const float*)d_in[6];
    const float* A_k = (const float*)d_in[7];
    const float* B_k = (const float*)d_in[8];
    const float* m_k = (const float*)d_in[9];
    const float* W_v = (const float*)d_in[10];
    const float* A_v = (const float*)d_in[11];
    const float* B_v = (const float*)d_in[12];
    const float* m_v = (const float*)d_in[13];

    float* ws = (float*)d_ws;
    float* wp   = ws + OFF_WP;
    float* raw  = ws + OFF_RAW;
    unsigned short* qlv = (unsigned short*)(ws + OFF_QLV);
    unsigned short* klv = (unsigned short*)(ws + OFF_KLV);
    unsigned short* vth = (unsigned short*)(ws + OFF_VTH);
    unsigned short* vtl = (unsigned short*)(ws + OFF_VTL);
    float2* rowstats = (float2*)(ws + OFF_RS);
    unsigned int* amax = (unsigned int*)(ws + OFF_AMAX);

    float* out_base  = (float*)d_out;          // (b, n, 512)
    float* attn_base = out_base + 4194304;     // (b, h, n, m)

    hipMemsetAsync(amax, 0, 3 * sizeof(unsigned int), stream);

    // Q
    build_wp_k<<<512, 256, 0, stream>>>(W_q, A_q, B_q, m_q, wp);
    proj_gemm_k<<<dim3(128, 8), 256, 0, stream>>>(x, wp, raw, amax + 0, 1);
    quant_levels_k<<<4096, 256, 0, stream>>>(raw, amax + 0, qlv, 1048576);
    // K
    build_wp_k<<<512, 256, 0, stream>>>(W_k, A_k, B_k, m_k, wp);
    proj_gemm_k<<<dim3(128, 8), 256, 0, stream>>>(x, wp, raw, amax + 1, 1);
    quant_levels_k<<<4096, 256, 0, stream>>>(raw, amax + 1, klv, 1048576);
    // V
    build_wp_k<<<512, 256, 0, stream>>>(W_v, A_v, B_v, m_v, wp);
    proj_gemm_k<<<dim3(128, 8), 256, 0, stream>>>(x, wp, raw, amax + 2, 0);
    vsplit_k<<<dim3(16, 64), 256, 0, stream>>>(raw, vth, vtl);

    attn_stats_k<<<dim3(16, 64), 256, 0, stream>>>(qlv, klv, adj, amax,
                                                   rowstats, amax + 2);
    attn_out_k<<<dim3(16, 64), 256, 0, stream>>>(qlv, klv, vth, vtl, adj, amax,
                                                 rowstats, attn_base, out_base);
}

// Round 3
// 805.779 us; speedup vs baseline: 1.8250x; 1.0366x over previous
//
#include <hip/hip_runtime.h>
#include <math.h>

// Problem constants: B=8, N=1024, FIN=FOUT=512, H=8, HD=64, BH=64

typedef __attribute__((ext_vector_type(8))) short short8;    // 8 bf16 (4 VGPRs)
typedef __attribute__((ext_vector_type(4))) float floatx4;   // MFMA C/D

// Workspace layout (float words)
#define OFF_WP    0                // 262144  (single reused W' buffer)
#define OFF_RAW   262144           // 4194304 (reused raw q/k/v projection)
#define OFF_QLV   4456448          // 2097152 floats = 4.2M bf16 levels
#define OFF_KLV   6553600
#define OFF_VTH   8650752          // v^T hi bf16 [bh][d][m]
#define OFF_VTL   10747904         // v^T lo bf16
#define OFF_RS    12845056         // 65536 float2 (row m, l)
#define OFF_AMAX  12976128         // 3 uints
#define OFF_BM    12976144         // 131072 uint64 adj bitmask (1 MB)

__device__ __forceinline__ unsigned short bf16_rne(float f) {
    unsigned int u = __float_as_uint(f);
    unsigned int r = u + 0x7fffu + ((u >> 16) & 1u);
    return (unsigned short)(r >> 16);
}
__device__ __forceinline__ float bf16_to_f(unsigned short h) {
    return __uint_as_float(((unsigned int)h) << 16);
}
// exact for values already representable in bf16 (integers |x|<=127)
__device__ __forceinline__ unsigned short bf16_exact(float f) {
    return (unsigned short)(__float_as_uint(f) >> 16);
}

__device__ __forceinline__ void outer4(float (&acc)[4][4], float4 a, float4 b) {
    float av[4] = {a.x, a.y, a.z, a.w};
    float bv[4] = {b.x, b.y, b.z, b.w};
#pragma unroll
    for (int i = 0; i < 4; ++i)
#pragma unroll
        for (int j = 0; j < 4; ++j)
            acc[i][j] = fmaf(av[i], bv[j], acc[i][j]);
}

// ---------------------------------------------------------------------------
// K0: adjacency (8,1024,1024) i32 -> bitmask (8,1024,16) u64. One word/wave.
// ---------------------------------------------------------------------------
__global__ __launch_bounds__(256) void adj_bits_k(
    const int* __restrict__ adj, unsigned long long* __restrict__ bm)
{
    int tid = threadIdx.x;
    int wv = tid >> 6, lane = tid & 63;
    size_t word = (size_t)blockIdx.x * 4 + wv;       // 131072 words total
    int a = adj[word * 64 + lane];
    unsigned long long m = __ballot(a != 0);
    if (lane == 0) bm[word] = m;
}

// ---------------------------------------------------------------------------
// K1: Wp row o = mag[o]/||W[o,:]+Bm[o,:]@A|| * (W[o,:]+Bm[o,:]@A)
// ---------------------------------------------------------------------------
__global__ __launch_bounds__(256) void build_wp_k(
    const float* __restrict__ W, const float* __restrict__ A,
    const float* __restrict__ Bm, const float* __restrict__ mag,
    float* __restrict__ Wp)
{
    __shared__ float brow[16];
    __shared__ __align__(16) float wd[512];
    __shared__ float red[5];
    int o = blockIdx.x;
    int tid = threadIdx.x;
    if (tid < 16) brow[tid] = Bm[o * 16 + tid];
    __syncthreads();
    float ss = 0.f;
    for (int i = tid; i < 512; i += 256) {
        float acc = W[o * 512 + i];
#pragma unroll
        for (int r = 0; r < 16; ++r) acc = fmaf(brow[r], A[r * 512 + i], acc);
        wd[i] = acc;
        ss = fmaf(acc, acc, ss);
    }
#pragma unroll
    for (int off = 32; off > 0; off >>= 1) ss += __shfl_down(ss, off);
    int lane = tid & 63, wv = tid >> 6;
    if (lane == 0) red[wv] = ss;
    __syncthreads();
    if (tid == 0) red[4] = mag[o] / sqrtf(red[0] + red[1] + red[2] + red[3]);
    __syncthreads();
    float scl = red[4];
    for (int i = tid; i < 512; i += 256) Wp[o * 512 + i] = wd[i] * scl;
}

// ---------------------------------------------------------------------------
// K2: y = x(8192x512) @ Wp^T, dst in (b,h,n,d) layout; optional absmax.
// ---------------------------------------------------------------------------
__global__ __launch_bounds__(256) void proj_gemm_k(
    const float* __restrict__ x, const float* __restrict__ Wp,
    float* __restrict__ dst, unsigned int* __restrict__ amaxp, int do_amax)
{
    __shared__ __align__(16) float xs[16][68];
    __shared__ __align__(16) float wsb[16][68];
    __shared__ float redmax[4];
    int tid = threadIdx.x;
    int tx = tid & 15, ty = tid >> 4;
    int t0 = blockIdx.x * 64, o0 = blockIdx.y * 64;
    float acc[4][4];
#pragma unroll
    for (int i = 0; i < 4; ++i)
#pragma unroll
        for (int j = 0; j < 4; ++j) acc[i][j] = 0.f;

    int r = tid >> 2, c4 = tid & 3;
    for (int k0 = 0; k0 < 512; k0 += 16) {
        float4 xv = *(const float4*)(x + (size_t)(t0 + r) * 512 + k0 + c4 * 4);
        float4 wv = *(const float4*)(Wp + (size_t)(o0 + r) * 512 + k0 + c4 * 4);
        xs[c4 * 4 + 0][r] = xv.x; xs[c4 * 4 + 1][r] = xv.y;
        xs[c4 * 4 + 2][r] = xv.z; xs[c4 * 4 + 3][r] = xv.w;
        wsb[c4 * 4 + 0][r] = wv.x; wsb[c4 * 4 + 1][r] = wv.y;
        wsb[c4 * 4 + 2][r] = wv.z; wsb[c4 * 4 + 3][r] = wv.w;
        __syncthreads();
#pragma unroll
        for (int kk = 0; kk < 16; ++kk) {
            float4 a = *(const float4*)&xs[kk][ty * 4];
            float4 b = *(const float4*)&wsb[kk][tx * 4];
            outer4(acc, a, b);
        }
        __syncthreads();
    }

    int h = o0 >> 6;
    float mx = 0.f;
#pragma unroll
    for (int i = 0; i < 4; ++i) {
        int t = t0 + ty * 4 + i;
        int b = t >> 10, n = t & 1023;
        float4 v4 = make_float4(acc[i][0], acc[i][1], acc[i][2], acc[i][3]);
        *(float4*)(dst + ((size_t)(b * 8 + h) * 1024 + n) * 64 + tx * 4) = v4;
        mx = fmaxf(mx, fmaxf(fmaxf(fabsf(v4.x), fabsf(v4.y)),
                             fmaxf(fabsf(v4.z), fabsf(v4.w))));
    }
    if (do_amax) {
#pragma unroll
        for (int off = 32; off > 0; off >>= 1) mx = fmaxf(mx, __shfl_down(mx, off));
        if ((tid & 63) == 0) redmax[tid >> 6] = mx;
        __syncthreads();
        if (tid == 0) {
            float m2 = fmaxf(fmaxf(redmax[0], redmax[1]), fmaxf(redmax[2], redmax[3]));
            atomicMax(amaxp, __float_as_uint(m2));
        }
    }
}

// ---------------------------------------------------------------------------
// K2b: raw fp32 -> int8 levels stored as exact bf16 (for MFMA operands)
// ---------------------------------------------------------------------------
__global__ __launch_bounds__(256) void quant_levels_k(
    const float* __restrict__ raw, const unsigned int* __restrict__ amaxp,
    unsigned short* __restrict__ lv, int n4)
{
    float scale = fmaxf(__uint_as_float(*amaxp) / 127.f, 1e-8f);
    int i = blockIdx.x * 256 + threadIdx.x;
    if (i >= n4) return;
    float4 v = ((const float4*)raw)[i];
    float l0 = fminf(fmaxf(rintf(v.x / scale), -127.f), 127.f);
    float l1 = fminf(fmaxf(rintf(v.y / scale), -127.f), 127.f);
    float l2 = fminf(fmaxf(rintf(v.z / scale), -127.f), 127.f);
    float l3 = fminf(fmaxf(rintf(v.w / scale), -127.f), 127.f);
    ushort4 o;
    o.x = bf16_exact(l0); o.y = bf16_exact(l1);
    o.z = bf16_exact(l2); o.w = bf16_exact(l3);
    ((ushort4*)lv)[i] = o;
}

// ---------------------------------------------------------------------------
// K2c: v (bh,n,64) fp32 -> transposed bf16 hi/lo (bh,d=64,m=1024)
// ---------------------------------------------------------------------------
__global__ __launch_bounds__(256) void vsplit_k(
    const float* __restrict__ vb, unsigned short* __restrict__ vth,
    unsigned short* __restrict__ vtl)
{
    __shared__ float ls[64][69];
    int tid = threadIdx.x;
    int mt = blockIdx.x, bh = blockIdx.y;
#pragma unroll
    for (int l = 0; l < 4; ++l) {
        int idx = l * 256 + tid;
        int r = idx >> 4, c4 = idx & 15;
        float4 v = *(const float4*)(vb + (size_t)(bh * 1024 + mt * 64 + r) * 64 + c4 * 4);
        ls[r][c4 * 4 + 0] = v.x; ls[r][c4 * 4 + 1] = v.y;
        ls[r][c4 * 4 + 2] = v.z; ls[r][c4 * 4 + 3] = v.w;
    }
    __syncthreads();
#pragma unroll
    for (int l = 0; l < 4; ++l) {
        int idx = l * 256 + tid;
        int d = idx >> 4, mg = idx & 15;
        ushort4 hi, lo;
        float v0 = ls[mg * 4 + 0][d], v1 = ls[mg * 4 + 1][d];
        float v2 = ls[mg * 4 + 2][d], v3 = ls[mg * 4 + 3][d];
        hi.x = bf16_rne(v0); lo.x = bf16_rne(v0 - bf16_to_f(hi.x));
        hi.y = bf16_rne(v1); lo.y = bf16_rne(v1 - bf16_to_f(hi.y));
        hi.z = bf16_rne(v2); lo.z = bf16_rne(v2 - bf16_to_f(hi.z));
        hi.w = bf16_rne(v3); lo.w = bf16_rne(v3 - bf16_to_f(hi.w));
        size_t ob = (size_t)(bh * 64 + d) * 1024 + mt * 64 + mg * 4;
        *(ushort4*)(vth + ob) = hi;
        *(ushort4*)(vtl + ob) = lo;
    }
}

// ---------------------------------------------------------------------------
// K3a: barrier-free MFMA scores + bitmask + tile-merged online softmax stats.
// Wave = 16 q rows x 1024 cols; A/B fragments loaded straight from global.
// ---------------------------------------------------------------------------
__global__ __launch_bounds__(256) void attn_stats_k(
    const unsigned short* __restrict__ qlv, const unsigned short* __restrict__ klv,
    const unsigned long long* __restrict__ bm, const unsigned int* __restrict__ amax,
    float2* __restrict__ rowstats, unsigned int* __restrict__ amax_attn)
{
    __shared__ float sred[4];
    int tid = threadIdx.x;
    int lane = tid & 63, w = tid >> 6;
    int m_ = lane & 15, quad = lane >> 4;
    int qt = blockIdx.x, bh = blockIdx.y;
    int b = bh >> 3;
    int rowbase = qt * 64 + w * 16;                  // wave's 16 q rows (in bh)
    float sq = fmaxf(__uint_as_float(amax[0]) / 127.f, 1e-8f);
    float sk = fmaxf(__uint_as_float(amax[1]) / 127.f, 1e-8f);
    float ss = sq * sk;

    const unsigned short* qp = qlv + ((size_t)bh * 1024 + rowbase + m_) * 64;
    short8 Aq0 = *(const short8*)(qp + quad * 8);
    short8 Aq1 = *(const short8*)(qp + 32 + quad * 8);
    const unsigned short* kbase = klv + (size_t)bh * 1024 * 64;
    const unsigned long long* bmb = bm + ((size_t)b * 1024 + rowbase) * 16;

    float mrun[4], lrun[4];
#pragma unroll
    for (int r = 0; r < 4; ++r) { mrun[r] = -1e9f; lrun[r] = 0.f; }

    for (int c = 0; c < 16; ++c) {
        unsigned long long mk[4];
#pragma unroll
        for (int r = 0; r < 4; ++r) mk[r] = bmb[(quad * 4 + r) * 16 + c];
        float sv[4][4];
#pragma unroll
        for (int s = 0; s < 4; ++s) {
            const unsigned short* kp = kbase + (size_t)(c * 64 + s * 16 + m_) * 64;
            short8 B0 = *(const short8*)(kp + quad * 8);
            short8 B1 = *(const short8*)(kp + 32 + quad * 8);
            floatx4 Cv = {0.f, 0.f, 0.f, 0.f};
            Cv = __builtin_amdgcn_mfma_f32_16x16x32_bf16(Aq0, B0, Cv, 0, 0, 0);
            Cv = __builtin_amdgcn_mfma_f32_16x16x32_bf16(Aq1, B1, Cv, 0, 0, 0);
            int colbit = s * 16 + m_;
#pragma unroll
            for (int r = 0; r < 4; ++r)
                sv[r][s] = ((mk[r] >> colbit) & 1ull) ? Cv[r] * ss : -1e9f;
        }
#pragma unroll
        for (int r = 0; r < 4; ++r) {
            float tm = fmaxf(fmaxf(sv[r][0], sv[r][1]), fmaxf(sv[r][2], sv[r][3]));
            float mn = fmaxf(mrun[r], tm);
            float e = __expf(sv[r][0] - mn) + __expf(sv[r][1] - mn)
                    + __expf(sv[r][2] - mn) + __expf(sv[r][3] - mn);
            lrun[r] = fmaf(lrun[r], __expf(mrun[r] - mn), e);
            mrun[r] = mn;
        }
    }

    float invmax = 0.f;
#pragma unroll
    for (int r = 0; r < 4; ++r) {
        float m = mrun[r], l = lrun[r];
#pragma unroll
        for (int off = 1; off < 16; off <<= 1) {
            float mo = __shfl_xor(m, off);
            float lo = __shfl_xor(l, off);
            float mn = fmaxf(m, mo);
            l = l * __expf(m - mn) + lo * __expf(mo - mn);
            m = mn;
        }
        if (m_ == 0)
            rowstats[(size_t)bh * 1024 + rowbase + quad * 4 + r] = make_float2(m, l);
        invmax = fmaxf(invmax, 1.0f / l);
    }
    invmax = fmaxf(invmax, __shfl_xor(invmax, 16));
    invmax = fmaxf(invmax, __shfl_xor(invmax, 32));
    if (lane == 0) sred[w] = invmax;
    __syncthreads();
    if (tid == 0)
        atomicMax(amax_attn, __float_as_uint(
            fmaxf(fmaxf(sred[0], sred[1]), fmaxf(sred[2], sred[3]))));
}

// ---------------------------------------------------------------------------
// K3b: barrier-free recompute (bit-identical scores), quantize attn (single
// HBM write), fused P@V via MFMA; P transposed through wave-private LDS
// (double-buffered, lgkmcnt-only sync), V fragments direct from global.
// ---------------------------------------------------------------------------
__global__ __launch_bounds__(256) void attn_out_k(
    const unsigned short* __restrict__ qlv, const unsigned short* __restrict__ klv,
    const unsigned short* __restrict__ vth, const unsigned short* __restrict__ vtl,
    const unsigned long long* __restrict__ bm, const unsigned int* __restrict__ amax,
    const float2* __restrict__ rowstats,
    float* __restrict__ attn, float* __restrict__ out)
{
    __shared__ unsigned short pl[4][2][16][68];      // [wave][dbuf][row][col(+pad)]
    int tid = threadIdx.x;
    int lane = tid & 63, w = tid >> 6;
    int m_ = lane & 15, quad = lane >> 4;
    int qt = blockIdx.x, bh = blockIdx.y;
    int b = bh >> 3, h = bh & 7;
    int rowbase = qt * 64 + w * 16;
    float sq = fmaxf(__uint_as_float(amax[0]) / 127.f, 1e-8f);
    float sk = fmaxf(__uint_as_float(amax[1]) / 127.f, 1e-8f);
    float ss = sq * sk;
    float sa = fmaxf(__uint_as_float(amax[2]) / 127.f, 1e-8f);
    float inv_sa = 1.0f / sa;

    const unsigned short* qp = qlv + ((size_t)bh * 1024 + rowbase + m_) * 64;
    short8 Aq0 = *(const short8*)(qp + quad * 8);
    short8 Aq1 = *(const short8*)(qp + 32 + quad * 8);
    const unsigned short* kbase = klv + (size_t)bh * 1024 * 64;
    const unsigned long long* bmb = bm + ((size_t)b * 1024 + rowbase) * 16;

    float mrow[4], rlr[4];
#pragma unroll
    for (int r = 0; r < 4; ++r) {
        float2 st = rowstats[(size_t)bh * 1024 + rowbase + quad * 4 + r];
        mrow[r] = st.x;
        rlr[r] = 1.0f / st.y;
    }
    floatx4 acc[4];
#pragma unroll
    for (int r = 0; r < 4; ++r) acc[r] = (floatx4){0.f, 0.f, 0.f, 0.f};

    float* attn_b = attn + ((size_t)bh << 20);

    for (int c = 0; c < 16; ++c) {
        unsigned long long mk[4];
#pragma unroll
        for (int r = 0; r < 4; ++r) mk[r] = bmb[(quad * 4 + r) * 16 + c];
        unsigned short* plw = &pl[w][c & 1][0][0];
#pragma unroll
        for (int s = 0; s < 4; ++s) {
            const unsigned short* kp = kbase + (size_t)(c * 64 + s * 16 + m_) * 64;
            short8 B0 = *(const short8*)(kp + quad * 8);
            short8 B1 = *(const short8*)(kp + 32 + quad * 8);
            floatx4 Cv = {0.f, 0.f, 0.f, 0.f};
            Cv = __builtin_amdgcn_mfma_f32_16x16x32_bf16(Aq0, B0, Cv, 0, 0, 0);
            Cv = __builtin_amdgcn_mfma_f32_16x16x32_bf16(Aq1, B1, Cv, 0, 0, 0);
            int colbit = s * 16 + m_;
            int col = c * 64 + colbit;
#pragma unroll
            for (int r = 0; r < 4; ++r) {
                int qrow = rowbase + quad * 4 + r;
                float sval = ((mk[r] >> colbit) & 1ull) ? Cv[r] * ss : -1e9f;
                float p = __expf(sval - mrow[r]) * rlr[r];
                float lv = fminf(rintf(p * inv_sa), 127.f);
                attn_b[((size_t)qrow << 10) + col] = lv * sa;
                plw[(quad * 4 + r) * 68 + colbit] = bf16_exact(lv);
            }
        }
        __asm__ volatile("s_waitcnt lgkmcnt(0)" ::: "memory");
        short8 Ap0 = *(const short8*)&pl[w][c & 1][m_][quad * 8];
        short8 Ap1 = *(const short8*)&pl[w][c & 1][m_][32 + quad * 8];
#pragma unroll
        for (int dt = 0; dt < 4; ++dt) {
            const unsigned short* vph = vth + ((size_t)(bh * 64 + dt * 16 + m_)) * 1024 + c * 64;
            const unsigned short* vpl = vtl + ((size_t)(bh * 64 + dt * 16 + m_)) * 1024 + c * 64;
            short8 Bh0 = *(const short8*)(vph + quad * 8);
            short8 Bh1 = *(const short8*)(vph + 32 + quad * 8);
            short8 Bl0 = *(const short8*)(vpl + quad * 8);
            short8 Bl1 = *(const short8*)(vpl + 32 + quad * 8);
            acc[dt] = __builtin_amdgcn_mfma_f32_16x16x32_bf16(Ap0, Bh0, acc[dt], 0, 0, 0);
            acc[dt] = __builtin_amdgcn_mfma_f32_16x16x32_bf16(Ap1, Bh1, acc[dt], 0, 0, 0);
            acc[dt] = __builtin_amdgcn_mfma_f32_16x16x32_bf16(Ap0, Bl0, acc[dt], 0, 0, 0);
            acc[dt] = __builtin_amdgcn_mfma_f32_16x16x32_bf16(Ap1, Bl1, acc[dt], 0, 0, 0);
        }
    }
#pragma unroll
    for (int dt = 0; dt < 4; ++dt)
#pragma unroll
        for (int r = 0; r < 4; ++r) {
            int n = rowbase + quad * 4 + r;
            int d = dt * 16 + m_;
            out[(size_t)(b * 1024 + n) * 512 + h * 64 + d] = acc[dt][r] * sa;
        }
}

// ---------------------------------------------------------------------------
extern "C" void kernel_launch(void* const* d_in, const int* in_sizes, int n_in,
                              void* d_out, int out_size, void* d_ws, size_t ws_size,
                              hipStream_t stream)
{
    (void)in_sizes; (void)n_in; (void)out_size; (void)ws_size;
    const float* x   = (const float*)d_in[0];
    const int*   adj = (const int*)d_in[1];
    const float* W_q = (const float*)d_in[2];
    const float* A_q = (const float*)d_in[3];
    const float* B_q = (const float*)d_in[4];
    const float* m_q = (const float*)d_in[5];
    const float* W_k = (const float*)d_in[6];
    const float* A_k = (const float*)d_in[7];
    const float* B_k = (const float*)d_in[8];
    const float* m_k = (const float*)d_in[9];
    const float* W_v = (const float*)d_in[10];
    const float* A_v = (const float*)d_in[11];
    const float* B_v = (const float*)d_in[12];
    const float* m_v = (const float*)d_in[13];

    float* ws = (float*)d_ws;
    float* wp   = ws + OFF_WP;
    float* raw  = ws + OFF_RAW;
    unsigned short* qlv = (unsigned short*)(ws + OFF_QLV);
    unsigned short* klv = (unsigned short*)(ws + OFF_KLV);
    unsigned short* vth = (unsigned short*)(ws + OFF_VTH);
    unsigned short* vtl = (unsigned short*)(ws + OFF_VTL);
    float2* rowstats = (float2*)(ws + OFF_RS);
    unsigned int* amax = (unsigned int*)(ws + OFF_AMAX);
    unsigned long long* bmask = (unsigned long long*)(ws + OFF_BM);

    float* out_base  = (float*)d_out;          // (b, n, 512)
    float* attn_base = out_base + 4194304;     // (b, h, n, m)

    hipMemsetAsync(amax, 0, 3 * sizeof(unsigned int), stream);

    adj_bits_k<<<32768, 256, 0, stream>>>(adj, bmask);

    // Q
    build_wp_k<<<512, 256, 0, stream>>>(W_q, A_q, B_q, m_q, wp);
    proj_gemm_k<<<dim3(128, 8), 256, 0, stream>>>(x, wp, raw, amax + 0, 1);
    quant_levels_k<<<4096, 256, 0, stream>>>(raw, amax + 0, qlv, 1048576);
    // K
    build_wp_k<<<512, 256, 0, stream>>>(W_k, A_k, B_k, m_k, wp);
    proj_gemm_k<<<dim3(128, 8), 256, 0, stream>>>(x, wp, raw, amax + 1, 1);
    quant_levels_k<<<4096, 256, 0, stream>>>(raw, amax + 1, klv, 1048576);
    // V
    build_wp_k<<<512, 256, 0, stream>>>(W_v, A_v, B_v, m_v, wp);
    proj_gemm_k<<<dim3(128, 8), 256, 0, stream>>>(x, wp, raw, amax + 2, 0);
    vsplit_k<<<dim3(16, 64), 256, 0, stream>>>(raw, vth, vtl);

    attn_stats_k<<<dim3(16, 64), 256, 0, stream>>>(qlv, klv, bmask, amax,
                                                   rowstats, amax + 2);
    attn_out_k<<<dim3(16, 64), 256, 0, stream>>>(qlv, klv, vth, vtl, bmask, amax,
                                                 rowstats, attn_base, out_base);
}